// Round 8
// baseline (927.218 us; speedup 1.0000x reference)
//
#include <hip/hip_runtime.h>

// ShootingBlockMNModel1 — single persistent kernel, register-resident data,
// two-level epoch grid barrier (per-group lines + global line), packed-f32
// math, rcp tanh, DPP wave reductions. Block 0 does the 12-dim backward
// recursion in-kernel between the last two barriers.
//
// ws (floats): part[21][36][256] @0, theta[21][12], pk[20][20],
//              then (aligned) unsigned barrier lines (memset to 0 each launch).

#define LR 0.25f
#define NIT 20
#define TPB 512
#define NBLK 256
#define NTH (NBLK*TPB)
#define NBR NBLK
#define SL 4

typedef float v2f __attribute__((ext_vector_type(2)));

__device__ __forceinline__ v2f tanh2(v2f x){
    v2f e;
    e.x = __expf(x.x + x.x);
    e.y = __expf(x.y + x.y);
    v2f d = e + 1.0f;
    v2f r;
    r.x = __builtin_amdgcn_rcpf(d.x);
    r.y = __builtin_amdgcn_rcpf(d.y);
    return 1.0f - (r + r);
}

#define DPP_ADD(x, ctrl) ((x) + __int_as_float(__builtin_amdgcn_update_dpp(0, __float_as_int(x), (ctrl), 0xF, 0xF, true)))
__device__ __forceinline__ float wave_sum64(float x){
    x = DPP_ADD(x, 0x111);
    x = DPP_ADD(x, 0x112);
    x = DPP_ADD(x, 0x114);
    x = DPP_ADD(x, 0x118);
    x = DPP_ADD(x, 0x142);
    x = DPP_ADD(x, 0x143);   // lane 63 = total
    return x;
}

__device__ __forceinline__ float ld_agent(const float* p){
    return __hip_atomic_load(p, __ATOMIC_RELAXED, __HIP_MEMORY_SCOPE_AGENT);
}

// two-level grid barrier; monotone epoch counters (memset once per launch).
// bar lines (32 uints = 128B each): [0..7]=group arrive, [8..15]=group release,
// [16]=global arrive, [17]=global release.
__device__ __forceinline__ void grid_barrier(unsigned* bar, unsigned epoch, int grp){
    __syncthreads();
    if(threadIdx.x==0){
        unsigned prev = __hip_atomic_fetch_add(&bar[grp*32], 1u,
                            __ATOMIC_ACQ_REL, __HIP_MEMORY_SCOPE_AGENT);
        if(prev == epoch*(NBLK/8) - 1u){
            unsigned p2 = __hip_atomic_fetch_add(&bar[16*32], 1u,
                              __ATOMIC_ACQ_REL, __HIP_MEMORY_SCOPE_AGENT);
            if(p2 == epoch*8u - 1u){
                __hip_atomic_store(&bar[17*32], epoch,
                                   __ATOMIC_RELEASE, __HIP_MEMORY_SCOPE_AGENT);
            }else{
                while(__hip_atomic_load(&bar[17*32], __ATOMIC_ACQUIRE,
                                        __HIP_MEMORY_SCOPE_AGENT) < epoch)
                    __builtin_amdgcn_s_sleep(8);
            }
            __hip_atomic_store(&bar[(8+grp)*32], epoch,
                               __ATOMIC_RELEASE, __HIP_MEMORY_SCOPE_AGENT);
        }else{
            while(__hip_atomic_load(&bar[(8+grp)*32], __ATOMIC_ACQUIRE,
                                    __HIP_MEMORY_SCOPE_AGENT) < epoch)
                __builtin_amdgcn_s_sleep(8);
        }
    }
    __syncthreads();
}

__device__ __forceinline__ void compute_grad(const float* s, const float* th,
                                             const float* ksym, const float* ksymb,
                                             float c, float* g){
    const float Ivec[4]={1.f,0.f,0.f,1.f};
    #pragma unroll
    for(int j=0;j<4;j++){
        float kv=0.f;
        #pragma unroll
        for(int m=0;m<4;m++) kv += ksym[j*4+m]*th[m];
        g[j] = kv - c*s[j];
    }
    #pragma unroll
    for(int i2=0;i2<2;i2++)
        g[4+i2] = ksymb[i2*2+0]*th[4] + ksymb[i2*2+1]*th[5] - c*s[4+i2];
    #pragma unroll
    for(int j=0;j<4;j++){
        float kv=0.f;
        #pragma unroll
        for(int m=0;m<4;m++) kv += ksym[j*4+m]*(th[6+m]-Ivec[m]);
        g[6+j] = kv - c*s[6+j];
    }
    #pragma unroll
    for(int i2=0;i2<2;i2++)
        g[10+i2] = ksymb[i2*2+0]*th[10] + ksymb[i2*2+1]*th[11] - c*s[10+i2];
}

__device__ __forceinline__ void accum_sample2(v2f Q0, v2f Q1, v2f P0, v2f P1,
    float t1_00,float t1_01,float t1_10,float t1_11,
    float t2_00,float t2_01,float t2_10,float t2_11,float b2_0,float b2_1,
    v2f* acc){
    v2f u0 = t2_00*Q0 + t2_01*Q1 + b2_0;
    v2f u1 = t2_10*Q0 + t2_11*Q1 + b2_1;
    v2f h0 = tanh2(u0), h1 = tanh2(u1);
    v2f s0 = 1.0f - h0*h0, s1 = 1.0f - h1*h1;
    v2f a0 = t1_00*P0 + t1_10*P1;
    v2f a1 = t1_01*P0 + t1_11*P1;
    v2f w0 = a0*s0, w1 = a1*s1;
    v2f r0 = -2.0f*(a0*h0)*s0, r1 = -2.0f*(a1*h1)*s1;
    acc[0]+=P0*h0; acc[1]+=P0*h1; acc[2]+=P1*h0; acc[3]+=P1*h1;
    acc[4]+=P0;    acc[5]+=P1;
    acc[6]+=w0*Q0; acc[7]+=w0*Q1; acc[8]+=w1*Q0; acc[9]+=w1*Q1;
    acc[10]+=w0;   acc[11]+=w1;
    v2f ps00=P0*s0, ps01=P0*s1, ps10=P1*s0, ps11=P1*s1;
    acc[12]+=ps00*Q0; acc[13]+=ps00*Q1; acc[14]+=ps01*Q0; acc[15]+=ps01*Q1;
    acc[16]+=ps10*Q0; acc[17]+=ps10*Q1; acc[18]+=ps11*Q0; acc[19]+=ps11*Q1;
    acc[20]+=ps00; acc[21]+=ps01; acc[22]+=ps10; acc[23]+=ps11;
    v2f r0q0=r0*Q0, r1q0=r1*Q0;
    acc[24]+=r0q0*Q0; acc[25]+=r0q0*Q1; acc[26]+=r0*(Q1*Q1);
    acc[27]+=r1q0*Q0; acc[28]+=r1q0*Q1; acc[29]+=r1*(Q1*Q1);
    acc[30]+=r0q0; acc[31]+=r0*Q1; acc[32]+=r1q0; acc[33]+=r1*Q1;
    acc[34]+=r0; acc[35]+=r1;
}

__device__ __forceinline__ void bk_step2(v2f Q0, v2f Q1, v2f P0, v2f P1,
    float t1_00,float t1_01,float t1_10,float t1_11,
    float t2_00,float t2_01,float t2_10,float t2_11,float b2_0,float b2_1,
    float L1_00,float L1_01,float L1_10,float L1_11,
    float L2_00,float L2_01,float L2_10,float L2_11,float lb2_0,float lb2_1,
    v2f &B0, v2f &B1){
    v2f u0 = t2_00*Q0 + t2_01*Q1 + b2_0;
    v2f u1 = t2_10*Q0 + t2_11*Q1 + b2_1;
    v2f h0 = tanh2(u0), h1 = tanh2(u1);
    v2f s0 = 1.0f - h0*h0, s1 = 1.0f - h1*h1;
    v2f a0 = t1_00*P0 + t1_10*P1;
    v2f a1 = t1_01*P0 + t1_11*P1;
    v2f w0 = a0*s0, w1 = a1*s1;
    v2f r0 = -2.0f*(a0*h0)*s0, r1 = -2.0f*(a1*h1)*s1;
    v2f lp0 = L1_00*P0 + L1_10*P1;
    v2f lp1 = L1_01*P0 + L1_11*P1;
    v2f z0 = L2_00*Q0 + L2_01*Q1 + lb2_0;
    v2f z1 = L2_10*Q0 + L2_11*Q1 + lb2_1;
    v2f m0 = lp0*s0 + r0*z0;
    v2f m1 = lp1*s1 + r1*z1;
    B0 += t2_00*m0 + t2_10*m1 + L2_00*w0 + L2_10*w1;
    B1 += t2_01*m0 + t2_11*m1 + L2_01*w0 + L2_11*w1;
}

__global__ __launch_bounds__(TPB, 2) void k_fused(
    const float4* __restrict__ q4, const float4* __restrict__ p4,
    const float4* __restrict__ x4, int nv4,
    const float* __restrict__ t1i, const float* __restrict__ b1i,
    const float* __restrict__ t2i, const float* __restrict__ b2i,
    const float* __restrict__ invK, const float* __restrict__ invKb,
    float* __restrict__ part, float* __restrict__ theta_g,
    float* __restrict__ pk_g, unsigned* __restrict__ bar,
    float4* __restrict__ oq, float4* __restrict__ op, float4* __restrict__ ox,
    float c)
{
    const int tid = threadIdx.x, bid = blockIdx.x;
    const int grp = bid & 7;
    const int lane = tid & 63, wave = tid >> 6;
    const int gtid = bid*TPB + tid;

    __shared__ float ths[12], sgv[12], tsum[12][33];
    __shared__ float red[TPB/64][36];
    __shared__ float ks[16], ksb[4];
    __shared__ float sums[(NIT+1)*36];
    __shared__ __align__(16) float pkS[NIT*20];

    // ---- register-resident data (loaded once) ----
    float4 qd[SL], pd[SL];
    bool val[SL];
    #pragma unroll
    for(int s=0;s<SL;s++){
        int j = gtid + s*NTH;
        val[s] = (j < nv4);
        int jc = val[s] ? j : 0;
        qd[s]=q4[jc]; pd[s]=p4[jc];
        if(!val[s]){ pd[s].x=0.f; pd[s].y=0.f; pd[s].z=0.f; pd[s].w=0.f; }
    }

    if(tid<16) ks[tid]  = 0.5f*(invK[tid]  + invK[(tid&3)*4 + (tid>>2)]);
    if(tid<4)  ksb[tid] = 0.5f*(invKb[tid] + invKb[(tid&1)*2 + (tid>>1)]);

    // ---- forward: 21 stat reductions, theta recomputed redundantly ----
    for(int k=0;k<=NIT;k++){
        if(k==0){
            if(tid<12){
                float v = (tid<4)? t1i[tid] : (tid<6)? b1i[tid-4]
                        : (tid<10)? t2i[tid-6] : b2i[tid-10];
                ths[tid] = v;
                if(bid==0) theta_g[tid] = v;
            }
        }else{
            if(tid < 384){
                int j = tid >> 5, ch = tid & 31;
                const float* col = part + (size_t)((k-1)*36 + j)*NBR;
                float s = 0.f;
                #pragma unroll
                for(int i=0;i<NBR/32;i++) s += ld_agent(&col[ch + i*32]);
                tsum[j][ch] = s;
            }
            __syncthreads();
            if(tid < 12){
                float s = 0.f;
                #pragma unroll
                for(int ch=0; ch<32; ch++) s += tsum[tid][ch];
                sgv[tid] = s;
            }
            __syncthreads();
            if(tid == 0){
                float g[12], tp[12];
                #pragma unroll
                for(int j=0;j<12;j++) tp[j] = ths[j];
                compute_grad(sgv, tp, ks, ksb, c, g);
                #pragma unroll
                for(int j=0;j<12;j++){
                    float t = tp[j] - LR*g[j];
                    ths[j] = t;
                    if(bid==0) theta_g[k*12+j] = t;
                }
            }
        }
        __syncthreads();

        const float t1_00=ths[0], t1_01=ths[1], t1_10=ths[2], t1_11=ths[3];
        const float t2_00=ths[6], t2_01=ths[7], t2_10=ths[8], t2_11=ths[9];
        const float b2_0=ths[10], b2_1=ths[11];

        v2f acc[36];
        #pragma unroll
        for(int j=0;j<36;j++) acc[j] = (v2f){0.f,0.f};
        #pragma unroll
        for(int s=0;s<SL;s++){
            v2f Q0={qd[s].x,qd[s].z}, Q1={qd[s].y,qd[s].w};
            v2f P0={pd[s].x,pd[s].z}, P1={pd[s].y,pd[s].w};
            accum_sample2(Q0,Q1,P0,P1,
                t1_00,t1_01,t1_10,t1_11,t2_00,t2_01,t2_10,t2_11,b2_0,b2_1,acc);
        }
        for(int j = SL*NTH + gtid; j < nv4; j += NTH){   // generic-size tail
            float4 qq=q4[j], pp=p4[j];
            v2f Q0={qq.x,qq.z}, Q1={qq.y,qq.w};
            v2f P0={pp.x,pp.z}, P1={pp.y,pp.w};
            accum_sample2(Q0,Q1,P0,P1,
                t1_00,t1_01,t1_10,t1_11,t2_00,t2_01,t2_10,t2_11,b2_0,b2_1,acc);
        }

        float wres[36];
        #pragma unroll
        for(int j=0;j<36;j++) wres[j] = wave_sum64(acc[j].x + acc[j].y);
        if(lane == 63){
            #pragma unroll
            for(int j=0;j<36;j++) red[wave][j] = wres[j];
        }
        __syncthreads();
        if(tid < 36){
            float sum = 0.f;
            #pragma unroll
            for(int w=0; w<TPB/64; w++) sum += red[w][tid];
            part[((size_t)k*36 + tid)*NBR + bid] = sum;
        }
        grid_barrier(bar, (unsigned)(k+1), grp);
    }

    // ---- backward recursion (block 0 only) ----
    if(bid == 0){
        for(int seg = wave; seg < (NIT+1)*36; seg += TPB/64){
            const float* base = part + (size_t)seg*NBR;
            float s = 0.f;
            #pragma unroll
            for(int i=0;i<NBR/64;i++) s += ld_agent(&base[lane + i*64]);
            s = wave_sum64(s);
            if(lane==63) sums[seg] = s;
        }
        __syncthreads();
        if(tid == 0){
            float lv[12];
            compute_grad(sums + 20*36, theta_g + 20*12, ks, ksb, c, lv);
            for(int k=NIT-1;k>=0;k--){
                const float* s = sums + k*36;
                const float* T = theta_g + k*12;
                float* P = pk_g + k*20;
                P[0]=T[0]; P[1]=T[1]; P[2]=T[2]; P[3]=T[3];
                P[4]=T[6]; P[5]=T[7]; P[6]=T[8]; P[7]=T[9];
                P[8]=T[10]; P[9]=T[11];
                P[10]=lv[0]; P[11]=lv[1]; P[12]=lv[2]; P[13]=lv[3];
                P[14]=lv[6]; P[15]=lv[7]; P[16]=lv[8]; P[17]=lv[9];
                P[18]=lv[10]; P[19]=lv[11];
                if(k==0) break;
                float H[12];
                for(int a=0;a<2;a++)for(int b=0;b<2;b++){
                    int j=a*2+b;
                    float data = s[12+a*4+b*2+0]*lv[6+b*2+0]
                               + s[12+a*4+b*2+1]*lv[6+b*2+1]
                               + s[20+a*2+b]*lv[10+b];
                    float kv=0.f;
                    for(int m=0;m<4;m++) kv += ks[j*4+m]*lv[m];
                    H[j]=kv - c*data;
                }
                H[4] = ksb[0]*lv[4] + ksb[1]*lv[5];
                H[5] = ksb[2]*lv[4] + ksb[3]*lv[5];
                for(int cc=0;cc<2;cc++)for(int d=0;d<2;d++){
                    int j=cc*2+d;
                    float term1 = lv[0+cc]*s[12+0*4+cc*2+d] + lv[2+cc]*s[12+1*4+cc*2+d];
                    float term2 = lv[6+cc*2+0]*s[24+cc*3+(0+d)] + lv[6+cc*2+1]*s[24+cc*3+(1+d)];
                    float term3 = lv[10+cc]*s[30+cc*2+d];
                    float kv=0.f;
                    for(int m=0;m<4;m++) kv += ks[j*4+m]*lv[6+m];
                    H[6+j]=kv - c*(term1+term2+term3);
                }
                for(int cc=0;cc<2;cc++){
                    float z1 = lv[0+cc]*s[20+0*2+cc] + lv[2+cc]*s[20+1*2+cc];
                    float z2 = lv[6+cc*2+0]*s[30+cc*2+0] + lv[6+cc*2+1]*s[30+cc*2+1];
                    float z3 = lv[10+cc]*s[34+cc];
                    float kv = ksb[cc*2+0]*lv[10] + ksb[cc*2+1]*lv[11];
                    H[10+cc]=kv - c*(z1+z2+z3);
                }
                for(int j=0;j<12;j++) lv[j] -= LR*H[j];
            }
        }
    }
    grid_barrier(bar, (unsigned)(NIT+2), grp);

    // ---- phase B: per-sample dot_p B-sums + outputs (q,p still in regs) ----
    for(int j=tid; j<NIT*20; j+=TPB) pkS[j] = ld_agent(&pk_g[j]);
    __syncthreads();

    float4 xd[SL];
    #pragma unroll
    for(int s=0;s<SL;s++){
        int j = gtid + s*NTH;
        xd[s] = x4[val[s] ? j : 0];
    }

    v2f B0[SL], B1[SL];
    #pragma unroll
    for(int s=0;s<SL;s++){ B0[s]=(v2f){0.f,0.f}; B1[s]=(v2f){0.f,0.f}; }

    #pragma unroll 4
    for(int k=0;k<NIT;k++){
        const float4* P4 = (const float4*)(pkS + k*20);
        float4 Pa=P4[0], Pb=P4[1], Pc=P4[2], Pd=P4[3], Pe=P4[4];
        float t1_00=Pa.x,t1_01=Pa.y,t1_10=Pa.z,t1_11=Pa.w;
        float t2_00=Pb.x,t2_01=Pb.y,t2_10=Pb.z,t2_11=Pb.w;
        float b2_0=Pc.x,b2_1=Pc.y;
        float L1_00=Pc.z,L1_01=Pc.w,L1_10=Pd.x,L1_11=Pd.y;
        float L2_00=Pd.z,L2_01=Pd.w,L2_10=Pe.x,L2_11=Pe.y,lb2_0=Pe.z,lb2_1=Pe.w;
        #pragma unroll
        for(int s=0;s<SL;s++){
            v2f Q0={qd[s].x,qd[s].z}, Q1={qd[s].y,qd[s].w};
            v2f P0={pd[s].x,pd[s].z}, P1={pd[s].y,pd[s].w};
            bk_step2(Q0,Q1,P0,P1,
                t1_00,t1_01,t1_10,t1_11,t2_00,t2_01,t2_10,t2_11,b2_0,b2_1,
                L1_00,L1_01,L1_10,L1_11,L2_00,L2_01,L2_10,L2_11,lb2_0,lb2_1,
                B0[s],B1[s]);
        }
    }

    {   // epilogue at theta_20 (ths still holds it)
        const float t1_00=ths[0],t1_01=ths[1],t1_10=ths[2],t1_11=ths[3];
        const float b1_0=ths[4],b1_1=ths[5];
        const float t2_00=ths[6],t2_01=ths[7],t2_10=ths[8],t2_11=ths[9];
        const float b2_0=ths[10],b2_1=ths[11];
        #pragma unroll
        for(int s=0;s<SL;s++){
            if(!val[s]) continue;
            int j = gtid + s*NTH;
            v2f Q0={qd[s].x,qd[s].z}, Q1={qd[s].y,qd[s].w};
            v2f P0={pd[s].x,pd[s].z}, P1={pd[s].y,pd[s].w};
            v2f u0 = t2_00*Q0 + t2_01*Q1 + b2_0;
            v2f u1 = t2_10*Q0 + t2_11*Q1 + b2_1;
            v2f h0 = tanh2(u0), h1 = tanh2(u1);
            v2f s0 = 1.0f-h0*h0, s1 = 1.0f-h1*h1;
            v2f a0 = t1_00*P0 + t1_10*P1;
            v2f a1 = t1_01*P0 + t1_11*P1;
            v2f w0 = a0*s0, w1 = a1*s1;
            v2f dq0 = t1_00*h0 + t1_01*h1 + b1_0;
            v2f dq1 = t1_10*h0 + t1_11*h1 + b1_1;
            v2f dp0 = c*(LR*B0[s] - (t2_00*w0 + t2_10*w1));
            v2f dp1 = c*(LR*B1[s] - (t2_01*w0 + t2_11*w1));
            oq[j] = make_float4(dq0.x, dq1.x, dq0.y, dq1.y);
            op[j] = make_float4(dp0.x, dp1.x, dp0.y, dp1.y);
            v2f X0={xd[s].x,xd[s].z}, X1={xd[s].y,xd[s].w};
            v2f xu0 = t2_00*X0 + t2_01*X1 + b2_0;
            v2f xu1 = t2_10*X0 + t2_11*X1 + b2_1;
            v2f xh0 = tanh2(xu0), xh1 = tanh2(xu1);
            v2f xd0 = t1_00*xh0 + t1_01*xh1 + b1_0;
            v2f xd1 = t1_10*xh0 + t1_11*xh1 + b1_1;
            ox[j] = make_float4(xd0.x, xd1.x, xd0.y, xd1.y);
        }
    }

    // generic-size tail (never runs at K=1M)
    for(int j = SL*NTH + gtid; j < nv4; j += NTH){
        float4 qq=q4[j], pp=p4[j], xx=x4[j];
        v2f Q0={qq.x,qq.z}, Q1={qq.y,qq.w};
        v2f P0={pp.x,pp.z}, P1={pp.y,pp.w};
        v2f Bt0={0.f,0.f}, Bt1={0.f,0.f};
        for(int k=0;k<NIT;k++){
            const float* P = pkS + k*20;
            bk_step2(Q0,Q1,P0,P1, P[0],P[1],P[2],P[3], P[4],P[5],P[6],P[7],P[8],P[9],
                     P[10],P[11],P[12],P[13], P[14],P[15],P[16],P[17],P[18],P[19],
                     Bt0,Bt1);
        }
        const float t1_00=ths[0],t1_01=ths[1],t1_10=ths[2],t1_11=ths[3];
        const float b1_0=ths[4],b1_1=ths[5];
        const float t2_00=ths[6],t2_01=ths[7],t2_10=ths[8],t2_11=ths[9];
        const float b2_0=ths[10],b2_1=ths[11];
        v2f u0 = t2_00*Q0 + t2_01*Q1 + b2_0;
        v2f u1 = t2_10*Q0 + t2_11*Q1 + b2_1;
        v2f h0 = tanh2(u0), h1 = tanh2(u1);
        v2f s0 = 1.0f-h0*h0, s1 = 1.0f-h1*h1;
        v2f a0 = t1_00*P0 + t1_10*P1;
        v2f a1 = t1_01*P0 + t1_11*P1;
        v2f w0 = a0*s0, w1 = a1*s1;
        v2f dq0 = t1_00*h0 + t1_01*h1 + b1_0;
        v2f dq1 = t1_10*h0 + t1_11*h1 + b1_1;
        v2f dp0 = c*(LR*Bt0 - (t2_00*w0 + t2_10*w1));
        v2f dp1 = c*(LR*Bt1 - (t2_01*w0 + t2_11*w1));
        oq[j] = make_float4(dq0.x, dq1.x, dq0.y, dq1.y);
        op[j] = make_float4(dp0.x, dp1.x, dp0.y, dp1.y);
        v2f X0={xx.x,xx.z}, X1={xx.y,xx.w};
        v2f xu0 = t2_00*X0 + t2_01*X1 + b2_0;
        v2f xu1 = t2_10*X0 + t2_11*X1 + b2_1;
        v2f xh0 = tanh2(xu0), xh1 = tanh2(xu1);
        v2f o0 = t1_00*xh0 + t1_01*xh1 + b1_0;
        v2f o1 = t1_10*xh0 + t1_11*xh1 + b1_1;
        ox[j] = make_float4(o0.x, o1.x, o0.y, o1.y);
    }
}

extern "C" void kernel_launch(void* const* d_in, const int* in_sizes, int n_in,
                              void* d_out, int out_size, void* d_ws, size_t ws_size,
                              hipStream_t stream) {
    const float* inp = (const float*)d_in[1];
    const int K = in_sizes[1]/6;
    const int nv4 = K >> 1;

    const float4* q4 = (const float4*)inp;
    const float4* p4 = (const float4*)(inp + 2*(size_t)K);
    const float4* x4 = (const float4*)(inp + 4*(size_t)K);

    float* part  = (float*)d_ws;                          // [21][36][256] = 193536 f
    float* theta = part + (size_t)(NIT+1)*36*NBR;         // [21][12]
    float* pk    = theta + 252;                           // [20][20]
    size_t barOff = (size_t)(NIT+1)*36*NBR + 252 + 400;
    barOff = (barOff + 31) & ~(size_t)31;                 // 128B align
    unsigned* bar = (unsigned*)((float*)d_ws + barOff);   // 18 lines x 32 uints
    const float c = 1.0f/(2.0f*(float)K);

    hipMemsetAsync(bar, 0, 18*32*sizeof(unsigned), stream);

    float* out = (float*)d_out;
    k_fused<<<NBLK, TPB, 0, stream>>>(q4, p4, x4, nv4,
        (const float*)d_in[2], (const float*)d_in[3],
        (const float*)d_in[4], (const float*)d_in[5],
        (const float*)d_in[6], (const float*)d_in[7],
        part, theta, pk, bar,
        (float4*)out, (float4*)(out + 2*(size_t)K), (float4*)(out + 4*(size_t)K),
        c);
}

// Round 9
// 282.669 us; speedup vs baseline: 3.2802x; 3.2802x over previous
//
#include <hip/hip_runtime.h>

// ShootingBlockMNModel1 — multi-kernel (kernel boundary = cheap grid barrier).
// 21 reduce passes (self-updating theta via head-fold of prev partials),
// k=20 pass also emits dot_q/dot_x at theta_20; backfold+adjoint recursion;
// k_final emits dot_p only (pk via uniform scalar loads, no LDS).
//
// ws (floats): part[21][36][NBR] @0, theta[21][12], pk[20][20]

#define LR 0.25f
#define NIT 20
#define RTPB 512
#define NBR 256

typedef float v2f __attribute__((ext_vector_type(2)));

__device__ __forceinline__ v2f tanh2(v2f x){
    v2f e;
    e.x = __expf(x.x + x.x);
    e.y = __expf(x.y + x.y);
    v2f d = e + 1.0f;
    v2f r;
    r.x = __builtin_amdgcn_rcpf(d.x);
    r.y = __builtin_amdgcn_rcpf(d.y);
    return 1.0f - (r + r);
}

#define DPP_ADD(x, ctrl) ((x) + __int_as_float(__builtin_amdgcn_update_dpp(0, __float_as_int(x), (ctrl), 0xF, 0xF, true)))
__device__ __forceinline__ float wave_sum64(float x){
    x = DPP_ADD(x, 0x111);
    x = DPP_ADD(x, 0x112);
    x = DPP_ADD(x, 0x114);
    x = DPP_ADD(x, 0x118);
    x = DPP_ADD(x, 0x142);
    x = DPP_ADD(x, 0x143);   // lane 63 = total
    return x;
}

__device__ __forceinline__ void compute_grad(const float* s, const float* th,
                                             const float* ksym, const float* ksymb,
                                             float c, float* g){
    const float Ivec[4]={1.f,0.f,0.f,1.f};
    #pragma unroll
    for(int j=0;j<4;j++){
        float kv=0.f;
        #pragma unroll
        for(int m=0;m<4;m++) kv += ksym[j*4+m]*th[m];
        g[j] = kv - c*s[j];
    }
    #pragma unroll
    for(int i2=0;i2<2;i2++)
        g[4+i2] = ksymb[i2*2+0]*th[4] + ksymb[i2*2+1]*th[5] - c*s[4+i2];
    #pragma unroll
    for(int j=0;j<4;j++){
        float kv=0.f;
        #pragma unroll
        for(int m=0;m<4;m++) kv += ksym[j*4+m]*(th[6+m]-Ivec[m]);
        g[6+j] = kv - c*s[6+j];
    }
    #pragma unroll
    for(int i2=0;i2<2;i2++)
        g[10+i2] = ksymb[i2*2+0]*th[10] + ksymb[i2*2+1]*th[11] - c*s[10+i2];
}

template<bool FULL>
__device__ __forceinline__ void accum_sample2(v2f Q0, v2f Q1, v2f P0, v2f P1,
    float t1_00,float t1_01,float t1_10,float t1_11,
    float t2_00,float t2_01,float t2_10,float t2_11,float b2_0,float b2_1,
    v2f* acc){
    v2f u0 = t2_00*Q0 + t2_01*Q1 + b2_0;
    v2f u1 = t2_10*Q0 + t2_11*Q1 + b2_1;
    v2f h0 = tanh2(u0), h1 = tanh2(u1);
    v2f s0 = 1.0f - h0*h0, s1 = 1.0f - h1*h1;
    v2f a0 = t1_00*P0 + t1_10*P1;
    v2f a1 = t1_01*P0 + t1_11*P1;
    v2f w0 = a0*s0, w1 = a1*s1;
    acc[0]+=P0*h0; acc[1]+=P0*h1; acc[2]+=P1*h0; acc[3]+=P1*h1;
    acc[4]+=P0;    acc[5]+=P1;
    acc[6]+=w0*Q0; acc[7]+=w0*Q1; acc[8]+=w1*Q0; acc[9]+=w1*Q1;
    acc[10]+=w0;   acc[11]+=w1;
    if(FULL){
        v2f r0 = -2.0f*(a0*h0)*s0, r1 = -2.0f*(a1*h1)*s1;
        v2f ps00=P0*s0, ps01=P0*s1, ps10=P1*s0, ps11=P1*s1;
        acc[12]+=ps00*Q0; acc[13]+=ps00*Q1; acc[14]+=ps01*Q0; acc[15]+=ps01*Q1;
        acc[16]+=ps10*Q0; acc[17]+=ps10*Q1; acc[18]+=ps11*Q0; acc[19]+=ps11*Q1;
        acc[20]+=ps00; acc[21]+=ps01; acc[22]+=ps10; acc[23]+=ps11;
        v2f r0q0=r0*Q0, r1q0=r1*Q0;
        acc[24]+=r0q0*Q0; acc[25]+=r0q0*Q1; acc[26]+=r0*(Q1*Q1);
        acc[27]+=r1q0*Q0; acc[28]+=r1q0*Q1; acc[29]+=r1*(Q1*Q1);
        acc[30]+=r0q0; acc[31]+=r0*Q1; acc[32]+=r1q0; acc[33]+=r1*Q1;
        acc[34]+=r0; acc[35]+=r1;
    }
}

// MODE 0: k=0 (light 12 sums, theta from inputs)
// MODE 1: k=1..19 (full 36 sums, head-fold theta update)
// MODE 2: k=20 (light 12 sums + dot_q/dot_x outputs at theta_20)
template<int MODE>
__global__ __launch_bounds__(RTPB) void k_reduce(
    const float4* __restrict__ q4, const float4* __restrict__ p4,
    const float4* __restrict__ x4, int nv4,
    const float* __restrict__ t1i, const float* __restrict__ b1i,
    const float* __restrict__ t2i, const float* __restrict__ b2i,
    const float* __restrict__ invK, const float* __restrict__ invKb,
    const float* __restrict__ theta_prev,
    const float* __restrict__ part_prev,    // [36][NBR] row k-1
    float* __restrict__ part_out,           // [36][NBR] row k
    float* __restrict__ theta_out,          // row k (block 0 persists)
    float4* __restrict__ oq, float4* __restrict__ ox,
    float c)
{
    constexpr bool FULL = (MODE==1);
    constexpr int NS = FULL ? 36 : 12;
    const int tid = threadIdx.x;
    const int NT = gridDim.x*RTPB;
    const int gtid = blockIdx.x*RTPB + tid;

    __shared__ float ths[12];
    __shared__ float sgv[12];
    __shared__ float tsum[12][33];
    __shared__ float red[RTPB/64][NS];
    __shared__ float ks[16], ksb[4];

    const bool structured = (nv4 == NBR*RTPB*4);
    float4 qd[4], pd[4];
    if(structured){
        #pragma unroll
        for(int s=0;s<4;s++){ qd[s]=q4[gtid + s*NT]; pd[s]=p4[gtid + s*NT]; }
    }

    if(MODE==0){
        if(tid < 12){
            float v = (tid<4)? t1i[tid] : (tid<6)? b1i[tid-4]
                    : (tid<10)? t2i[tid-6] : b2i[tid-10];
            ths[tid] = v;
            if(blockIdx.x==0) theta_out[tid] = v;
        }
        __syncthreads();
    }else{
        if(tid < 16) ks[tid]  = 0.5f*(invK[tid]  + invK[(tid&3)*4 + (tid>>2)]);
        if(tid < 4)  ksb[tid] = 0.5f*(invKb[tid] + invKb[(tid&1)*2 + (tid>>1)]);
        if(tid < 12*32){
            int j = tid >> 5, ch = tid & 31;
            const float* col = part_prev + j*NBR;
            float s = 0.f;
            #pragma unroll
            for(int i = 0; i < NBR/32; i++) s += col[ch + i*32];
            tsum[j][ch] = s;
        }
        __syncthreads();
        if(tid < 12){
            float s = 0.f;
            #pragma unroll
            for(int ch=0; ch<32; ch++) s += tsum[tid][ch];
            sgv[tid] = s;
        }
        __syncthreads();
        if(tid == 0){
            float g[12], tp[12];
            #pragma unroll
            for(int j=0;j<12;j++) tp[j] = theta_prev[j];
            compute_grad(sgv, tp, ks, ksb, c, g);
            #pragma unroll
            for(int j=0;j<12;j++){
                float t = tp[j] - LR*g[j];
                ths[j] = t;
                if(blockIdx.x==0) theta_out[j] = t;
            }
        }
        __syncthreads();
    }

    const float t1_00=ths[0], t1_01=ths[1], t1_10=ths[2], t1_11=ths[3];
    const float t2_00=ths[6], t2_01=ths[7], t2_10=ths[8], t2_11=ths[9];
    const float b2_0=ths[10], b2_1=ths[11];

    v2f acc[NS];
    #pragma unroll
    for(int j=0;j<NS;j++) acc[j] = (v2f){0.f, 0.f};

    if(structured){
        #pragma unroll
        for(int s=0;s<4;s++){
            v2f Q0={qd[s].x,qd[s].z}, Q1={qd[s].y,qd[s].w};
            v2f P0={pd[s].x,pd[s].z}, P1={pd[s].y,pd[s].w};
            accum_sample2<FULL>(Q0,Q1,P0,P1,
                t1_00,t1_01,t1_10,t1_11,t2_00,t2_01,t2_10,t2_11,b2_0,b2_1,acc);
        }
    }else{
        for(int j = gtid; j < nv4; j += NT){
            float4 qq = q4[j], pp = p4[j];
            v2f Q0={qq.x,qq.z}, Q1={qq.y,qq.w};
            v2f P0={pp.x,pp.z}, P1={pp.y,pp.w};
            accum_sample2<FULL>(Q0,Q1,P0,P1,
                t1_00,t1_01,t1_10,t1_11,t2_00,t2_01,t2_10,t2_11,b2_0,b2_1,acc);
        }
    }

    const int wave = tid >> 6;
    float wres[NS];
    #pragma unroll
    for(int j=0;j<NS;j++) wres[j] = wave_sum64(acc[j].x + acc[j].y);
    if((tid & 63) == 63){
        #pragma unroll
        for(int j=0;j<NS;j++) red[wave][j] = wres[j];
    }
    __syncthreads();
    if(tid < NS){
        float sum = 0.f;
        #pragma unroll
        for(int w=0; w<RTPB/64; w++) sum += red[w][tid];
        part_out[tid*NBR + blockIdx.x] = sum;
    }

    if(MODE==2){
        // dot_q and dot_x at theta_20 (q already in registers; load x here)
        const float b1_0=ths[4], b1_1=ths[5];
        if(structured){
            float4 xd[4];
            #pragma unroll
            for(int s=0;s<4;s++) xd[s] = x4[gtid + s*NT];
            #pragma unroll
            for(int s=0;s<4;s++){
                int j = gtid + s*NT;
                v2f Q0={qd[s].x,qd[s].z}, Q1={qd[s].y,qd[s].w};
                v2f u0 = t2_00*Q0 + t2_01*Q1 + b2_0;
                v2f u1 = t2_10*Q0 + t2_11*Q1 + b2_1;
                v2f h0 = tanh2(u0), h1 = tanh2(u1);
                v2f dq0 = t1_00*h0 + t1_01*h1 + b1_0;
                v2f dq1 = t1_10*h0 + t1_11*h1 + b1_1;
                oq[j] = make_float4(dq0.x, dq1.x, dq0.y, dq1.y);
                v2f X0={xd[s].x,xd[s].z}, X1={xd[s].y,xd[s].w};
                v2f xu0 = t2_00*X0 + t2_01*X1 + b2_0;
                v2f xu1 = t2_10*X0 + t2_11*X1 + b2_1;
                v2f xh0 = tanh2(xu0), xh1 = tanh2(xu1);
                v2f o0 = t1_00*xh0 + t1_01*xh1 + b1_0;
                v2f o1 = t1_10*xh0 + t1_11*xh1 + b1_1;
                ox[j] = make_float4(o0.x, o1.x, o0.y, o1.y);
            }
        }else{
            for(int j = gtid; j < nv4; j += NT){
                float4 qq = q4[j], xx = x4[j];
                v2f Q0={qq.x,qq.z}, Q1={qq.y,qq.w};
                v2f u0 = t2_00*Q0 + t2_01*Q1 + b2_0;
                v2f u1 = t2_10*Q0 + t2_11*Q1 + b2_1;
                v2f h0 = tanh2(u0), h1 = tanh2(u1);
                v2f dq0 = t1_00*h0 + t1_01*h1 + b1_0;
                v2f dq1 = t1_10*h0 + t1_11*h1 + b1_1;
                oq[j] = make_float4(dq0.x, dq1.x, dq0.y, dq1.y);
                v2f X0={xx.x,xx.z}, X1={xx.y,xx.w};
                v2f xu0 = t2_00*X0 + t2_01*X1 + b2_0;
                v2f xu1 = t2_10*X0 + t2_11*X1 + b2_1;
                v2f xh0 = tanh2(xu0), xh1 = tanh2(xu1);
                v2f o0 = t1_00*xh0 + t1_01*xh1 + b1_0;
                v2f o1 = t1_10*xh0 + t1_11*xh1 + b1_1;
                ox[j] = make_float4(o0.x, o1.x, o0.y, o1.y);
            }
        }
    }
}

// fold partials + 12-dim adjoint recursion + pack pk[k]
__global__ __launch_bounds__(1024) void k_backfold(
    const float* __restrict__ part,
    const float* __restrict__ thetaAll,
    const float* __restrict__ invK, const float* __restrict__ invKb,
    float* __restrict__ pk_g, float c)
{
    const int tid = threadIdx.x;
    const int wave = tid >> 6, lane = tid & 63;
    __shared__ float sums[(NIT+1)*36];
    __shared__ float ks[16], ksb[4];
    if(tid < 16) ks[tid]  = 0.5f*(invK[tid]  + invK[(tid&3)*4 + (tid>>2)]);
    if(tid < 4)  ksb[tid] = 0.5f*(invKb[tid] + invKb[(tid&1)*2 + (tid>>1)]);

    for(int seg = wave; seg < (NIT+1)*36; seg += 16){
        int row = seg/36, col = seg - row*36;
        float s = 0.f;
        if(col < 12 || (row >= 1 && row <= 19)){      // rows 0/20 only 12 cols
            const float* base = part + (size_t)seg*NBR;
            #pragma unroll
            for(int i = 0; i < NBR/64; i++) s += base[lane + i*64];
            s = wave_sum64(s);
        }
        if(lane == 63) sums[seg] = s;
    }
    __syncthreads();

    if(tid == 0){
        float lv[12];
        compute_grad(sums + 20*36, thetaAll + 20*12, ks, ksb, c, lv);
        for(int k=NIT-1;k>=0;k--){
            const float* s = sums + k*36;
            const float* T = thetaAll + k*12;
            float* P = pk_g + k*20;
            P[0]=T[0]; P[1]=T[1]; P[2]=T[2]; P[3]=T[3];
            P[4]=T[6]; P[5]=T[7]; P[6]=T[8]; P[7]=T[9];
            P[8]=T[10]; P[9]=T[11];
            P[10]=lv[0]; P[11]=lv[1]; P[12]=lv[2]; P[13]=lv[3];
            P[14]=lv[6]; P[15]=lv[7]; P[16]=lv[8]; P[17]=lv[9];
            P[18]=lv[10]; P[19]=lv[11];
            if(k==0) break;                           // lambda_0 never used
            float H[12];
            for(int a=0;a<2;a++)for(int b=0;b<2;b++){
                int j=a*2+b;
                float data = s[12+a*4+b*2+0]*lv[6+b*2+0]
                           + s[12+a*4+b*2+1]*lv[6+b*2+1]
                           + s[20+a*2+b]*lv[10+b];
                float kv=0.f;
                for(int m=0;m<4;m++) kv += ks[j*4+m]*lv[m];
                H[j]=kv - c*data;
            }
            H[4] = ksb[0]*lv[4] + ksb[1]*lv[5];
            H[5] = ksb[2]*lv[4] + ksb[3]*lv[5];
            for(int cc=0;cc<2;cc++)for(int d=0;d<2;d++){
                int j=cc*2+d;
                float term1 = lv[0+cc]*s[12+0*4+cc*2+d] + lv[2+cc]*s[12+1*4+cc*2+d];
                float term2 = lv[6+cc*2+0]*s[24+cc*3+(0+d)] + lv[6+cc*2+1]*s[24+cc*3+(1+d)];
                float term3 = lv[10+cc]*s[30+cc*2+d];
                float kv=0.f;
                for(int m=0;m<4;m++) kv += ks[j*4+m]*lv[6+m];
                H[6+j]=kv - c*(term1+term2+term3);
            }
            for(int cc=0;cc<2;cc++){
                float z1 = lv[0+cc]*s[20+0*2+cc] + lv[2+cc]*s[20+1*2+cc];
                float z2 = lv[6+cc*2+0]*s[30+cc*2+0] + lv[6+cc*2+1]*s[30+cc*2+1];
                float z3 = lv[10+cc]*s[34+cc];
                float kv = ksb[cc*2+0]*lv[10] + ksb[cc*2+1]*lv[11];
                H[10+cc]=kv - c*(z1+z2+z3);
            }
            for(int j=0;j<12;j++) lv[j] -= LR*H[j];
        }
    }
}

__device__ __forceinline__ void bk_step2(v2f Q0, v2f Q1, v2f P0, v2f P1,
    float t1_00,float t1_01,float t1_10,float t1_11,
    float t2_00,float t2_01,float t2_10,float t2_11,float b2_0,float b2_1,
    float L1_00,float L1_01,float L1_10,float L1_11,
    float L2_00,float L2_01,float L2_10,float L2_11,float lb2_0,float lb2_1,
    v2f &B0, v2f &B1){
    v2f u0 = t2_00*Q0 + t2_01*Q1 + b2_0;
    v2f u1 = t2_10*Q0 + t2_11*Q1 + b2_1;
    v2f h0 = tanh2(u0), h1 = tanh2(u1);
    v2f s0 = 1.0f - h0*h0, s1 = 1.0f - h1*h1;
    v2f a0 = t1_00*P0 + t1_10*P1;
    v2f a1 = t1_01*P0 + t1_11*P1;
    v2f w0 = a0*s0, w1 = a1*s1;
    v2f r0 = -2.0f*(a0*h0)*s0, r1 = -2.0f*(a1*h1)*s1;
    v2f lp0 = L1_00*P0 + L1_10*P1;
    v2f lp1 = L1_01*P0 + L1_11*P1;
    v2f z0 = L2_00*Q0 + L2_01*Q1 + lb2_0;
    v2f z1 = L2_10*Q0 + L2_11*Q1 + lb2_1;
    v2f m0 = lp0*s0 + r0*z0;
    v2f m1 = lp1*s1 + r1*z1;
    B0 += t2_00*m0 + t2_10*m1 + L2_00*w0 + L2_10*w1;
    B1 += t2_01*m0 + t2_11*m1 + L2_01*w0 + L2_11*w1;
}

// dot_p only; pk/theta20 via uniform (scalar) loads, no LDS.
__global__ __launch_bounds__(256) void k_final(
    const float4* __restrict__ q4, const float4* __restrict__ p4, int nv4,
    const float4* __restrict__ pk4,       // [NIT][5]
    const float4* __restrict__ th20_4,    // [3] theta row 20
    float4* __restrict__ op, float c)
{
    const int j = blockIdx.x*blockDim.x + threadIdx.x;
    if(j >= nv4) return;
    float4 qq=q4[j], pp=p4[j];
    v2f Q0={qq.x,qq.z}, Q1={qq.y,qq.w}, P0={pp.x,pp.z}, P1={pp.y,pp.w};
    v2f B0={0.f,0.f}, B1={0.f,0.f};
    #pragma unroll 5
    for(int k=0;k<NIT;k++){
        float4 Pa=pk4[k*5+0], Pb=pk4[k*5+1], Pc=pk4[k*5+2], Pd=pk4[k*5+3], Pe=pk4[k*5+4];
        bk_step2(Q0,Q1,P0,P1,
                 Pa.x,Pa.y,Pa.z,Pa.w,          // T1
                 Pb.x,Pb.y,Pb.z,Pb.w,          // T2
                 Pc.x,Pc.y,                    // b2
                 Pc.z,Pc.w,Pd.x,Pd.y,          // Lam1
                 Pd.z,Pd.w,Pe.x,Pe.y,          // Lam2
                 Pe.z,Pe.w,                    // lb2
                 B0,B1);
    }
    float4 Ta=th20_4[0], Tb=th20_4[1], Tc=th20_4[2];
    v2f u0 = Tb.z*Q0 + Tb.w*Q1 + Tc.z;
    v2f u1 = Tc.x*Q0 + Tc.y*Q1 + Tc.w;
    v2f h0 = tanh2(u0), h1 = tanh2(u1);
    v2f s0 = 1.0f - h0*h0, s1 = 1.0f - h1*h1;
    v2f a0 = Ta.x*P0 + Ta.z*P1;
    v2f a1 = Ta.y*P0 + Ta.w*P1;
    v2f w0 = a0*s0, w1 = a1*s1;
    v2f dp0 = c*(LR*B0 - (Tb.z*w0 + Tc.x*w1));
    v2f dp1 = c*(LR*B1 - (Tb.w*w0 + Tc.y*w1));
    op[j] = make_float4(dp0.x, dp1.x, dp0.y, dp1.y);
}

extern "C" void kernel_launch(void* const* d_in, const int* in_sizes, int n_in,
                              void* d_out, int out_size, void* d_ws, size_t ws_size,
                              hipStream_t stream) {
    const float* inp = (const float*)d_in[1];
    const int K = in_sizes[1]/6;
    const int nv4 = K >> 1;

    const float4* q4 = (const float4*)inp;
    const float4* p4 = (const float4*)(inp + 2*(size_t)K);
    const float4* x4 = (const float4*)(inp + 4*(size_t)K);

    float* part  = (float*)d_ws;                                   // [21][36][NBR]
    float* theta = part + (size_t)(NIT+1)*36*NBR;                  // [21][12]
    float* pk    = theta + 252;                                    // [20][20]
    const float c = 1.0f/(2.0f*(float)K);

    const float* t1i = (const float*)d_in[2];
    const float* b1i = (const float*)d_in[3];
    const float* t2i = (const float*)d_in[4];
    const float* b2i = (const float*)d_in[5];
    const float* invK = (const float*)d_in[6];
    const float* invKb= (const float*)d_in[7];

    float* out = (float*)d_out;
    float4* oq = (float4*)out;
    float4* op = (float4*)(out + 2*(size_t)K);
    float4* ox = (float4*)(out + 4*(size_t)K);

    for(int k=0;k<=NIT;k++){
        const float* th_prev = (k==0) ? nullptr : theta + (k-1)*12;
        const float* pt_prev = (k==0) ? nullptr : part + (size_t)(k-1)*36*NBR;
        float* po = part + (size_t)k*36*NBR;
        float* to = theta + k*12;
        if(k==0)
            k_reduce<0><<<NBR,RTPB,0,stream>>>(q4, p4, x4, nv4,
                t1i, b1i, t2i, b2i, invK, invKb, th_prev, pt_prev, po, to, oq, ox, c);
        else if(k==NIT)
            k_reduce<2><<<NBR,RTPB,0,stream>>>(q4, p4, x4, nv4,
                t1i, b1i, t2i, b2i, invK, invKb, th_prev, pt_prev, po, to, oq, ox, c);
        else
            k_reduce<1><<<NBR,RTPB,0,stream>>>(q4, p4, x4, nv4,
                t1i, b1i, t2i, b2i, invK, invKb, th_prev, pt_prev, po, to, oq, ox, c);
    }
    k_backfold<<<1,1024,0,stream>>>(part, theta, invK, invKb, pk, c);

    int fblk = (nv4 + 255)/256;
    k_final<<<fblk,256,0,stream>>>(q4, p4, nv4,
                                   (const float4*)pk, (const float4*)(theta + NIT*12),
                                   op, c);
}